// Round 16
// baseline (299.394 us; speedup 1.0000x reference)
//
#include <hip/hip_runtime.h>

#define HW 65536
#define CH 64
#define NPIXF 4194304.0f

typedef __attribute__((ext_vector_type(8))) short short8;
typedef __attribute__((ext_vector_type(4))) short short4v;
typedef __attribute__((ext_vector_type(8))) __bf16 bf16x8;
typedef __attribute__((ext_vector_type(4))) float f32x4;

__device__ __forceinline__ unsigned short f2bf(float f) {
  unsigned int u = __builtin_bit_cast(unsigned int, f);
  u += 0x7FFFu + ((u >> 16) & 1u);
  return (unsigned short)(u >> 16);
}
__device__ __forceinline__ short cvt1(float f) {
  return __builtin_bit_cast(short, (__bf16)f);
}
__device__ __forceinline__ float fastrcp(float f) {
  return __builtin_amdgcn_rcpf(f);
}
__device__ __forceinline__ int swz(int p, int cc) { return cc ^ ((p ^ (p >> 3)) & 7); }

// ws layout (floats):
//   stats: wsf[16*s+0]=sum_x +1=sumsq_x +2=sum_h +3=sumsq_h  (64B line/sample, memset-zeroed)
//   consts: u1=wsf[256..319]  v1=wsf[320..383]  u2=wsf[384..399]  v2=wsf[400..415]
//   a1 bf16[64][64] @2048, a2 bf16[16][64] @10240
//   scratch h-stat sink (diagnostic z>0 copies): floats 3072..3327 (bytes 12288..13311)
// need = 16384 B.

// ---- k1: x stats (streaming, full occupancy); block (0,0) preps weights ----
__global__ __launch_bounds__(256, 8) void k1(
    const float* __restrict__ x,
    const float* __restrict__ w1, const float* __restrict__ b1,
    const float* __restrict__ s1, const float* __restrict__ gb1,
    const float* __restrict__ w2, const float* __restrict__ b2,
    const float* __restrict__ s2, const float* __restrict__ gb2,
    float* __restrict__ wsf,
    unsigned short* __restrict__ a1, unsigned short* __restrict__ a2) {
  __shared__ float red[8];
  const int tid = threadIdx.x;
  const int l = tid & 63, w = tid >> 6;
  const int b = blockIdx.y;

  if (blockIdx.x == 0 && b == 0) {
    {
      int o = tid >> 2, q = tid & 3;
      float u = 0.f, v = 0.f;
      unsigned short loc[16];
#pragma unroll
      for (int i = 0; i < 16; ++i) {
        int c = q * 16 + i;
        float wv = w1[o * 64 + c];
        float wsc = wv * s1[c];
        loc[i] = f2bf(wsc);
        u += wsc;
        v += wv * gb1[c];
      }
      *(short8*)(a1 + o * 64 + q * 16) = *(short8*)loc;
      *(short8*)(a1 + o * 64 + q * 16 + 8) = *(short8*)(loc + 8);
      u += __shfl_xor(u, 1, 64); u += __shfl_xor(u, 2, 64);
      v += __shfl_xor(v, 1, 64); v += __shfl_xor(v, 2, 64);
      if (q == 0) { wsf[256 + o] = u; wsf[320 + o] = b1[o] + v; }
    }
    if (tid < 64) {
      int o = tid >> 2, q = tid & 3;
      float u = 0.f, v = 0.f;
      unsigned short loc[16];
#pragma unroll
      for (int i = 0; i < 16; ++i) {
        int c = q * 16 + i;
        float wv = (o < 6) ? w2[o * 64 + c] : 0.f;
        float wsc = wv * s2[c];
        loc[i] = f2bf(wsc);
        u += wsc;
        v += wv * gb2[c];
      }
      *(short8*)(a2 + o * 64 + q * 16) = *(short8*)loc;
      *(short8*)(a2 + o * 64 + q * 16 + 8) = *(short8*)(loc + 8);
      u += __shfl_xor(u, 1, 64); u += __shfl_xor(u, 2, 64);
      v += __shfl_xor(v, 1, 64); v += __shfl_xor(v, 2, 64);
      if (q == 0) { wsf[384 + o] = u; wsf[400 + o] = ((o < 6) ? b2[o] : 0.f) + v; }
    }
  }

  const f32x4* xb = (const f32x4*)(x + (size_t)b * CH * HW);
  const f32x4* p = xb + (size_t)blockIdx.x * 8192 + tid;
  float s = 0.f, q = 0.f;
#pragma unroll
  for (int it = 0; it < 32; ++it) {
    f32x4 v = p[it * 256];
#pragma unroll
    for (int i = 0; i < 4; ++i) { float f = v[i]; s += f; q += f * f; }
  }
#pragma unroll
  for (int off = 32; off > 0; off >>= 1) {
    s += __shfl_down(s, off, 64);
    q += __shfl_down(q, off, 64);
  }
  if (l == 0) { red[w] = s; red[4 + w] = q; }
  __syncthreads();
  if (tid == 0) {
    atomicAdd(wsf + 16 * b + 0, red[0] + red[1] + red[2] + red[3]);
    atomicAdd(wsf + 16 * b + 1, red[4] + red[5] + red[6] + red[7]);
  }
}

// ---- k2: R15 wave-private pipeline; gridDim.z replicates for DIAGNOSTIC counters ----
// All GN1 stats are final before k2 starts, so every z-copy computes identical y;
// z>0 copies process permuted samples and sink their h-stats to scratch.
__global__ __launch_bounds__(256, 3) void k2(const float* __restrict__ x,
                                             const unsigned short* __restrict__ a1,
                                             const unsigned short* __restrict__ a2,
                                             const float* __restrict__ wsf,
                                             float* __restrict__ wstat_real,
                                             float* __restrict__ wstat_scratch,
                                             float* __restrict__ out) {
  __shared__ __align__(16) unsigned char buf[2][128 * 128];
  __shared__ float red[8];
  const int tid = threadIdx.x;
  const int l = tid & 63, w = tid >> 6;
  const int z = blockIdx.z;
  const int s = ((15 - blockIdx.y) + 5 * z) & 15;   // permuted per copy
  float* wstat = z ? wstat_scratch : wstat_real;
  const int pbase = (127 - blockIdx.x) * 512;
  const float* xb = x + (size_t)s * CH * HW;

  const float m1 = wsf[16 * s + 0] / NPIXF;
  const float rs1 = rsqrtf(wsf[16 * s + 1] / NPIXF - m1 * m1 + 1e-6f);

  float c1r[4][4];
#pragma unroll
  for (int mf = 0; mf < 4; ++mf) {
    const int o0 = mf * 16 + (l >> 4) * 4;
    f32x4 u = *(const f32x4*)(wsf + 256 + o0);
    f32x4 vv = *(const f32x4*)(wsf + 320 + o0);
#pragma unroll
    for (int r = 0; r < 4; ++r) c1r[mf][r] = vv[r] - rs1 * m1 * u[r];
  }

  bf16x8 af[4][2];
#pragma unroll
  for (int mf = 0; mf < 4; ++mf)
#pragma unroll
    for (int ks = 0; ks < 2; ++ks)
      af[mf][ks] = *(const bf16x8*)((const unsigned char*)a1 +
                     (mf * 16 + (l & 15)) * 128 + ks * 64 + (l >> 4) * 16);
  bf16x8 a2f[2];
#pragma unroll
  for (int ks = 0; ks < 2; ++ks)
    a2f[ks] = *(const bf16x8*)((const unsigned char*)a2 +
                 (l & 15) * 128 + ks * 64 + (l >> 4) * 16);

  const int c0 = (l >> 3) * 8;
  const int px4 = (l & 7) * 4;
  const int prow = w * 32;
  const float* base = xb + (size_t)c0 * HW + pbase + prow + px4;
  float* ob = out + (size_t)s * 6 * HW;

  f32x4 v[8];
#pragma unroll
  for (int i = 0; i < 8; ++i) v[i] = *(const f32x4*)(base + (size_t)i * HW);
#pragma unroll
  for (int dp = 0; dp < 4; ++dp) {
    int p = prow + px4 + dp;
    short8 w8;
#pragma unroll
    for (int i = 0; i < 8; ++i) w8[i] = cvt1(v[i][dp]);
    *(short8*)(buf[0] + p * 128 + swz(p, c0 >> 3) * 16) = w8;
  }

  float hs = 0.f, hq = 0.f;
#pragma unroll
  for (int j = 0; j < 4; ++j) {
    const int cur = j & 1;
    const int pt = pbase + j * 128;

    if (j < 3) {
#pragma unroll
      for (int i = 0; i < 8; ++i)
        v[i] = *(const f32x4*)(base + (size_t)i * HW + (j + 1) * 128);
    }

    bf16x8 bfr[2][2];
#pragma unroll
    for (int nf = 0; nf < 2; ++nf) {
      const int pl = prow + nf * 16 + (l & 15);
#pragma unroll
      for (int ks = 0; ks < 2; ++ks) {
        int cc = ks * 4 + (l >> 4);
        bfr[nf][ks] = *(const bf16x8*)(buf[cur] + pl * 128 + swz(pl, cc) * 16);
      }
    }

#pragma unroll
    for (int nf = 0; nf < 2; ++nf) {
      const int pl = prow + nf * 16 + (l & 15);
#pragma unroll
      for (int mf = 0; mf < 4; ++mf) {
        f32x4 acc = {0.f, 0.f, 0.f, 0.f};
        acc = __builtin_amdgcn_mfma_f32_16x16x32_bf16(af[mf][0], bfr[nf][0], acc, 0, 0, 0);
        acc = __builtin_amdgcn_mfma_f32_16x16x32_bf16(af[mf][1], bfr[nf][1], acc, 0, 0, 0);
        const int o0 = mf * 16 + (l >> 4) * 4;
        short4v hv;
#pragma unroll
        for (int r = 0; r < 4; ++r) {
          float zz = rs1 * acc[r] + c1r[mf][r];
          float hh = zz * fastrcp(1.f + __expf(-zz));
          hs += hh; hq += hh * hh;
          hv[r] = cvt1(hh);
        }
        *(short4v*)(buf[cur] + pl * 128 + swz(pl, o0 >> 3) * 16 + (o0 & 7) * 2) = hv;
      }
    }

#pragma unroll
    for (int nf = 0; nf < 2; ++nf) {
      const int pl = prow + nf * 16 + (l & 15);
      bf16x8 hfr[2];
#pragma unroll
      for (int ks = 0; ks < 2; ++ks) {
        int cc = ks * 4 + (l >> 4);
        hfr[ks] = *(const bf16x8*)(buf[cur] + pl * 128 + swz(pl, cc) * 16);
      }
      f32x4 acc = {0.f, 0.f, 0.f, 0.f};
      acc = __builtin_amdgcn_mfma_f32_16x16x32_bf16(a2f[0], hfr[0], acc, 0, 0, 0);
      acc = __builtin_amdgcn_mfma_f32_16x16x32_bf16(a2f[1], hfr[1], acc, 0, 0, 0);
      const int ob0 = (l >> 4) * 4;
#pragma unroll
      for (int r = 0; r < 4; ++r) {
        int o = ob0 + r;
        if (o < 6) ob[(size_t)o * HW + pt + pl] = acc[r];
      }
    }

    if (j < 3) {
#pragma unroll
      for (int dp = 0; dp < 4; ++dp) {
        int p = prow + px4 + dp;
        short8 w8;
#pragma unroll
        for (int i = 0; i < 8; ++i) w8[i] = cvt1(v[i][dp]);
        *(short8*)(buf[cur ^ 1] + p * 128 + swz(p, c0 >> 3) * 16) = w8;
      }
    }
  }

#pragma unroll
  for (int off = 32; off > 0; off >>= 1) {
    hs += __shfl_down(hs, off, 64);
    hq += __shfl_down(hq, off, 64);
  }
  if (l == 0) { red[w] = hs; red[4 + w] = hq; }
  __syncthreads();
  if (tid == 0) {
    atomicAdd(wstat + 16 * s + 2, red[0] + red[1] + red[2] + red[3]);
    atomicAdd(wstat + 16 * s + 3, red[4] + red[5] + red[6] + red[7]);
  }
}

// ---- k3: out = rs2*out + c2[o]  (in-place, elementwise) ----
__global__ __launch_bounds__(256) void k3(float* __restrict__ out,
                                          const float* __restrict__ wsf) {
  const int s = 15 - blockIdx.y;
  const float m2 = wsf[16 * s + 2] / NPIXF;
  const float rs2 = rsqrtf(wsf[16 * s + 3] / NPIXF - m2 * m2 + 1e-6f);
  float* ob = out + (size_t)s * 6 * HW;
#pragma unroll
  for (int it = 0; it < 4; ++it) {
    int f4 = blockIdx.x * 256 + threadIdx.x + it * 24576;  // < 98304
    int o = f4 >> 14;
    float c2 = wsf[400 + o] - rs2 * m2 * wsf[384 + o];
    f32x4* p = (f32x4*)ob + f4;
    f32x4 v = *p;
#pragma unroll
    for (int i = 0; i < 4; ++i) v[i] = rs2 * v[i] + c2;
    *p = v;
  }
}

extern "C" void kernel_launch(void* const* d_in, const int* in_sizes, int n_in,
                              void* d_out, int out_size, void* d_ws, size_t ws_size,
                              hipStream_t stream) {
  const float* x  = (const float*)d_in[0];
  const float* s1 = (const float*)d_in[1];
  const float* g1 = (const float*)d_in[2];
  const float* w1 = (const float*)d_in[3];
  const float* b1 = (const float*)d_in[4];
  const float* s2 = (const float*)d_in[5];
  const float* g2 = (const float*)d_in[6];
  const float* w2 = (const float*)d_in[7];
  const float* b2 = (const float*)d_in[8];
  float* out = (float*)d_out;
  float* wsf = (float*)d_ws;
  unsigned short* a1 = (unsigned short*)((char*)d_ws + 2048);
  unsigned short* a2 = (unsigned short*)((char*)d_ws + 10240);
  float* wscratch = (float*)((char*)d_ws + 12288);  // z>0 h-stat sink (never read)

  if (ws_size < 16384) return;

  hipMemsetAsync(d_ws, 0, 1024, stream);  // zero per-sample stat lines
  k1<<<dim3(128, 16), 256, 0, stream>>>(x, w1, b1, s1, g1, w2, b2, s2, g2, wsf, a1, a2);
  // DIAGNOSTIC: z=3 replication so one ~3x-long k2 dispatch surfaces in top-5 with counters
  k2<<<dim3(128, 16, 3), 256, 0, stream>>>(x, a1, a2, wsf, wsf, wscratch, out);
  k3<<<dim3(96, 16), 256, 0, stream>>>(out, wsf);
}